// Round 8
// baseline (286.163 us; speedup 1.0000x reference)
//
#include <hip/hip_runtime.h>
#include <cstdint>
#include <cstddef>

typedef _Float16 f16;
typedef _Float16 f16x8 __attribute__((ext_vector_type(8)));
typedef _Float16 f16x4 __attribute__((ext_vector_type(4)));
typedef float    f32x4 __attribute__((ext_vector_type(4)));

#define S_CTX 2048
#define NH 16
#define DH 128

#define BAR() asm volatile("s_barrier" ::: "memory")
#define VMW(n) asm volatile("s_waitcnt vmcnt(" #n ")" ::: "memory")
#define MF(a, b, c) __builtin_amdgcn_mfma_f32_16x16x32_f16((a), (b), (c), 0, 0, 0)

__device__ __forceinline__ void gload16(const void* g, void* l) {
  __builtin_amdgcn_global_load_lds(
      (const __attribute__((address_space(1))) void*)g,
      (__attribute__((address_space(3))) void*)l, 16, 0, 0);
}

// ---------- prep: rope tables + x->f16 + 4x weight transpose, one dispatch ----------
__global__ void prep(const float* __restrict__ x,
                     const float* __restrict__ w0, const float* __restrict__ w1,
                     const float* __restrict__ w2, const float* __restrict__ w3,
                     f16* __restrict__ xb,
                     f16* __restrict__ o0, f16* __restrict__ o1,
                     f16* __restrict__ o2, f16* __restrict__ o3,
                     float* __restrict__ sint, float* __restrict__ cost) {
  const int bid = blockIdx.x, tid = threadIdx.x;
  if (bid < 512) {                       // rope tables: 2048*64
    int idx = bid * 256 + tid;
    int j = idx & 63, s = idx >> 6;
    float invf = __expf(-(float)(2 * j) * (1.0f / 128.0f) * 9.210340371976184f);
    float a = (float)s * invf;
    sint[idx] = sinf(a);
    cost[idx] = cosf(a);
  } else if (bid < 8704) {               // x fp32 -> fp16
    int i = ((bid - 512) * 256 + tid) * 4;
    float4 v = *(const float4*)(x + i);
    f16x4 o; o[0] = (f16)v.x; o[1] = (f16)v.y; o[2] = (f16)v.z; o[3] = (f16)v.w;
    *(f16x4*)(xb + i) = o;
  } else {                               // W[k][n] fp32 -> Wt[n][k] fp16
    int b2 = bid - 8704;
    int z = b2 >> 12, rem = b2 & 4095;
    int by = rem >> 6, bx = rem & 63;
    int tx = tid & 31, ty = tid >> 5;
    const float* in; f16* out;
    switch (z) {
      case 0: in = w0; out = o0; break;
      case 1: in = w1; out = o1; break;
      case 2: in = w2; out = o2; break;
      default: in = w3; out = o3; break;
    }
    __shared__ float tl[32][33];
    int xc = bx * 32 + tx, yc = by * 32 + ty;
#pragma unroll
    for (int r = 0; r < 32; r += 8)
      tl[ty + r][tx] = in[(size_t)(yc + r) * 2048 + xc];
    __syncthreads();
    int xo = by * 32 + tx, yo = bx * 32 + ty;
#pragma unroll
    for (int r = 0; r < 32; r += 8)
      out[(size_t)(yo + r) * 2048 + xo] = (f16)tl[tx][ty + r];
  }
}

// ---------- fused QKV GEMM: 256^2 tile, 8 waves (2M x 4N), per-wave 128x64 ----------
// grid (24,16): gcol = bx*256 in [0,6144); proj = gcol>>11 (0=Q,1=K,2=V).
// 384 blocks = 1.5 rounds. K in 64 halves of 32. Ring depth-3 x 32KB = 96 KB.
// 4 loads/thr/half, stage-ahead-2, counted vmcnt(4); tail 4/4/0/nop.
// Epilogues: proj<2 -> RoPE (pair (d,d+64) = acc[i][j]/acc[i][j+2]); proj=2 ->
// V^T via LDS transpose in two 128-col halves (R4-proven layout + swizzle).
__global__ __launch_bounds__(512, 1)
void gemm_qkv(const f16* __restrict__ A, const f16* __restrict__ wqT,
              const f16* __restrict__ wkT, const f16* __restrict__ wvT,
              f16* __restrict__ qb, f16* __restrict__ kb, f16* __restrict__ vtb,
              const float* __restrict__ sint, const float* __restrict__ cost) {
  extern __shared__ __align__(16) char lds[];
  const int tid = threadIdx.x, lane = tid & 63;
  const int wvi = tid >> 6, wm = wvi >> 2, wn = wvi & 3;
  const int gcol = blockIdx.x * 256;
  const int proj = gcol >> 11;
  const int col0 = gcol & 2047;
  const int row0 = blockIdx.y * 256;
  const f16* Bt = (proj == 0) ? wqT : ((proj == 1) ? wkT : wvT);

  const int ca0 = tid, ca1 = tid + 512;
  const int ra0 = ca0 >> 2, ra1 = ca1 >> 2;
  const int sa0 = (ca0 & 3) ^ ((ra0 >> 1) & 3);
  const int sa1 = (ca1 & 3) ^ ((ra1 >> 1) & 3);
  const f16* gA0 = A + (size_t)(row0 + ra0) * 2048 + sa0 * 8;
  const f16* gA1 = A + (size_t)(row0 + ra1) * 2048 + sa1 * 8;
  const f16* gB0 = Bt + (size_t)(col0 + ra0) * 2048 + sa0 * 8;
  const f16* gB1 = Bt + (size_t)(col0 + ra1) * 2048 + sa1 * 8;

  const int kslot = lane >> 4;
  int aoff[8], boff[4];
#pragma unroll
  for (int i = 0; i < 8; i++) {
    int row = wm * 128 + i * 16 + (lane & 15);
    aoff[i] = row * 64 + ((kslot ^ ((row >> 1) & 3)) << 4);
  }
#pragma unroll
  for (int j = 0; j < 4; j++) {
    int rb = (wn >> 1) * 128 + (wn & 1) * 32 + (j & 1) * 16 + (j >> 1) * 64 + (lane & 15);
    boff[j] = rb * 64 + ((kslot ^ ((rb >> 1) & 3)) << 4);
  }

  f32x4 acc[8][4] = {};

#define QKPH(SLOT, HS, SSLOT, DOSTAGE, WN) do {                                \
    const char* As_ = lds + (SLOT) * 32768;                                    \
    const char* Bs_ = As_ + 16384;                                             \
    f16x8 af[8], bf[4];                                                        \
    _Pragma("unroll") for (int i_ = 0; i_ < 8; i_++)                           \
      af[i_] = *(const f16x8*)(As_ + aoff[i_]);                                \
    _Pragma("unroll") for (int j_ = 0; j_ < 4; j_++)                           \
      bf[j_] = *(const f16x8*)(Bs_ + boff[j_]);                                \
    if (DOSTAGE) {                                                             \
      char* dA = lds + (SSLOT) * 32768;                                        \
      gload16(gA0 + (HS) * 32, dA + ca0 * 16);                                 \
      gload16(gA1 + (HS) * 32, dA + ca1 * 16);                                 \
      gload16(gB0 + (HS) * 32, dA + 16384 + ca0 * 16);                         \
      gload16(gB1 + (HS) * 32, dA + 16384 + ca1 * 16);                         \
    }                                                                          \
    asm volatile("s_waitcnt vmcnt(" #WN ")" ::: "memory");                     \
    BAR();                                                                     \
    __builtin_amdgcn_s_setprio(1);                                             \
    _Pragma("unroll") for (int i_ = 0; i_ < 8; i_++)                           \
      _Pragma("unroll") for (int j_ = 0; j_ < 4; j_++)                         \
        acc[i_][j_] = MF(af[i_], bf[j_], acc[i_][j_]);                         \
    __builtin_amdgcn_s_setprio(0);                                             \
    BAR();                                                                     \
  } while (0)

#pragma unroll
  for (int h = 0; h < 2; h++) {
    char* dA = lds + h * 32768;
    gload16(gA0 + h * 32, dA + ca0 * 16);
    gload16(gA1 + h * 32, dA + ca1 * 16);
    gload16(gB0 + h * 32, dA + 16384 + ca0 * 16);
    gload16(gB1 + h * 32, dA + 16384 + ca1 * 16);
  }
  VMW(4); BAR();

  for (int t = 0; t < 20; ++t) {
    const int hb = 3 * t;
    QKPH(0, hb + 2, 2, 1, 4);
    QKPH(1, hb + 3, 0, 1, 4);
    QKPH(2, hb + 4, 1, 1, 4);
  }
  QKPH(0, 62, 2, 1, 4);
  QKPH(1, 63, 0, 1, 4);
  QKPH(2, 0, 0, 0, 0);
  QKPH(0, 0, 0, 0, 63);
#undef QKPH

  const int b = row0 >> 11, sb = row0 & 2047;

  if (proj < 2) {
    // RoPE epilogue
    f16* dst = proj ? kb : qb;
    const int h = (col0 >> 7) + (wn >> 1);
#pragma unroll
    for (int i = 0; i < 8; i++)
#pragma unroll
      for (int jj = 0; jj < 2; jj++)
#pragma unroll
        for (int r = 0; r < 4; r++) {
          int s = sb + wm * 128 + i * 16 + (lane >> 4) * 4 + r;
          int d = (wn & 1) * 32 + jj * 16 + (lane & 15);
          float cv = cost[s * 64 + d], sv = sint[s * 64 + d];
          float x1 = acc[i][jj][r], x2 = acc[i][jj + 2][r];
          size_t base = ((size_t)(b * NH + h) * S_CTX + s) << 7;
          dst[base + d]      = (f16)(x1 * cv - x2 * sv);
          dst[base + d + 64] = (f16)(x2 * cv + x1 * sv);
        }
  } else {
    // V^T epilogue: 256 s-rows x 256 d-cols -> vtb[b,h,d,s], in two 128-col halves
    // (LDS [128 col][64 su] f16x4 = 64 KB; R4-proven (col<<1)&63 swizzle).
    const int h0 = col0 >> 7;
    f16x4* ldsv = (f16x4*)lds;
    for (int hh = 0; hh < 2; hh++) {
      BAR();
      if ((wn >> 1) == hh) {
#pragma unroll
        for (int i = 0; i < 8; i++)
#pragma unroll
          for (int j = 0; j < 4; j++) {
            f16x4 v;
#pragma unroll
            for (int r = 0; r < 4; r++) v[r] = (f16)acc[i][j][r];
            int coll = (wn & 1) * 32 + (j & 1) * 16 + (j >> 1) * 64 + (lane & 15);
            int su = wm * 32 + i * 4 + (lane >> 4);
            ldsv[coll * 64 + (su ^ ((coll << 1) & 63))] = v;
          }
      }
      BAR();
#pragma unroll
      for (int it = 0; it < 8; ++it) {
        int o = it * 512 + tid;            // [0,4096): coll = o>>5, s8 = o&31
        int coll = o >> 5, s8 = o & 31;
        int xc = (coll << 1) & 63;
        f16x4 lo = ldsv[coll * 64 + ((2 * s8) ^ xc)];
        f16x4 hi = ldsv[coll * 64 + ((2 * s8 + 1) ^ xc)];
        f16x8 vv;
        vv[0] = lo[0]; vv[1] = lo[1]; vv[2] = lo[2]; vv[3] = lo[3];
        vv[4] = hi[0]; vv[5] = hi[1]; vv[6] = hi[2]; vv[7] = hi[3];
        *(f16x8*)&vtb[((size_t)(b * NH + h0 + hh) * DH + coll) * S_CTX + sb + s8 * 8] = vv;
      }
    }
  }
}

// ---------- 8-phase GEMM, tile 256x128: MODE 2 = f32 epilogue (out-projection) ----------
template<int MODE>
__global__ __launch_bounds__(512, 1)
void gemm8(const f16* __restrict__ A, const f16* __restrict__ Bt,
           f16* __restrict__ vtb, float* __restrict__ of) {
  extern __shared__ __align__(16) char lds[];
#define RING_A(e) (lds + (e) * 16384)
#define RING_B(e) (lds + 65536 + (e) * 8192)
  const int tid = threadIdx.x, lane = tid & 63;
  const int wvi = tid >> 6, wm = wvi >> 1, wn = wvi & 1;
  const int col0 = blockIdx.x * 128;
  const int row0 = blockIdx.y * 256;

  const int ca0 = tid, ca1 = tid + 512, cb0 = tid;
  const int rAs0 = ca0 >> 2, rAs1 = ca1 >> 2, rBs0 = cb0 >> 2;
  const int sA0 = (ca0 & 3) ^ ((rAs0 >> 1) & 3);
  const int sA1 = (ca1 & 3) ^ ((rAs1 >> 1) & 3);
  const int sB0 = (cb0 & 3) ^ ((rBs0 >> 1) & 3);
  const f16* gA0 = A + (size_t)(row0 + rAs0) * 2048 + sA0 * 8;
  const f16* gA1 = A + (size_t)(row0 + rAs1) * 2048 + sA1 * 8;
  const f16* gB0 = Bt + (size_t)(col0 + rBs0) * 2048 + sB0 * 8;

  const int kslot = lane >> 4;
  int aoff[4], boff[4];
#pragma unroll
  for (int i = 0; i < 4; i++) {
    int row = wm * 64 + i * 16 + (lane & 15);
    aoff[i] = row * 64 + ((kslot ^ ((row >> 1) & 3)) << 4);
  }
#pragma unroll
  for (int j = 0; j < 4; j++) {
    int rb = wn * 32 + (j & 1) * 16 + (j >> 1) * 64 + (lane & 15);
    boff[j] = rb * 64 + ((kslot ^ ((rb >> 1) & 3)) << 4);
  }

  f32x4 acc[4][4] = {};

#define PH8(SLOT, HS, DOSTAGE, WN) do {                                        \
    const char* As_ = RING_A(SLOT);                                            \
    const char* Bs_ = RING_B(SLOT);                                            \
    f16x8 af[4], bf[4];                                                        \
    _Pragma("unroll") for (int i_ = 0; i_ < 4; i_++)                           \
      af[i_] = *(const f16x8*)(As_ + aoff[i_]);                                \
    _Pragma("unroll") for (int j_ = 0; j_ < 4; j_++)                           \
      bf[j_] = *(const f16x8*)(Bs_ + boff[j_]);                                \
    if (DOSTAGE) {                                                             \
      gload16(gA0 + (HS) * 32, RING_A((HS) & 3) + ca0 * 16);                   \
      gload16(gA1 + (HS) * 32, RING_A((HS) & 3) + ca1 * 16);                   \
      gload16(gB0 + (HS) * 32, RING_B((HS) & 3) + cb0 * 16);                   \
    }                                                                          \
    asm volatile("s_waitcnt vmcnt(" #WN ")" ::: "memory");                     \
    BAR();                                                                     \
    __builtin_amdgcn_s_setprio(1);                                             \
    _Pragma("unroll") for (int i_ = 0; i_ < 4; i_++)                           \
      _Pragma("unroll") for (int j_ = 0; j_ < 4; j_++)                         \
        acc[i_][j_] = MF(af[i_], bf[j_], acc[i_][j_]);                         \
    __builtin_amdgcn_s_setprio(0);                                             \
    BAR();                                                                     \
  } while (0)

#pragma unroll
  for (int h = 0; h < 3; h++) {
    gload16(gA0 + h * 32, RING_A(h) + ca0 * 16);
    gload16(gA1 + h * 32, RING_A(h) + ca1 * 16);
    gload16(gB0 + h * 32, RING_B(h) + cb0 * 16);
  }
  VMW(6); BAR();

  for (int t = 0; t < 15; ++t) {
    const int p = t * 4;
    PH8(0, p + 3, 1, 6);
    PH8(1, p + 4, 1, 6);
    PH8(2, p + 5, 1, 6);
    PH8(3, p + 6, 1, 6);
  }
  PH8(0, 63, 1, 6);
  PH8(1, 0, 0, 3);
  PH8(2, 0, 0, 0);
  PH8(3, 0, 0, 63);
#undef PH8

#pragma unroll
  for (int i = 0; i < 4; i++)
#pragma unroll
    for (int j = 0; j < 4; j++)
#pragma unroll
      for (int r = 0; r < 4; r++) {
        int row = row0 + wm * 64 + i * 16 + (lane >> 4) * 4 + r;
        int col = col0 + wn * 32 + (j & 1) * 16 + (j >> 1) * 64 + (lane & 15);
        of[(size_t)row * 2048 + col] = acc[i][j][r];
      }
  (void)vtb;
#undef RING_A
#undef RING_B
}

// ---------- flash attention (R6-proven): 8 waves, 128-row q-tiles, K/V dbuf ----------
// grid (8, 32). Block bx handles q128-tile bx then 15-bx -> 34 uniform KV64 iters.
__global__ __launch_bounds__(512)
void attn_k(const f16* __restrict__ q, const f16* __restrict__ kk,
            const f16* __restrict__ vt, f16* __restrict__ ctx) {
  __shared__ __align__(16) f16 Ks[2][64 * 128];   // [kv][d], slot ^= kv&7
  __shared__ __align__(16) f16 Vs[2][128 * 64];   // [d][kv], slot ^= d&7
  __shared__ __align__(16) f16 Pl[8][16 * 64];    // per wave [qr][kv], slot ^= qr&7
  const int tid = threadIdx.x, lane = tid & 63, wv = tid >> 6;
  const int bh = blockIdx.y;
  const int b = bh >> 4, h = bh & 15;
  const size_t plane = (size_t)bh * (S_CTX * DH);
  const f16* Qp = q + plane;
  const f16* Kp = kk + plane;
  const f16* Vp = vt + plane;
  const float LOG2E = 1.4426950408889634f;

  const int ck0 = tid, ck1 = tid + 512;
  const int cv0 = tid, cv1 = tid + 512;

  for (int half = 0; half < 2; half++) {
    const int Q = half ? (15 - (int)blockIdx.x) : (int)blockIdx.x;
    const int q0 = Q * 128;
    const int NT = 2 * Q + 2;

    f16x8 qf[4];
    {
      const f16* qq = Qp + (size_t)(q0 + wv * 16 + (lane & 15)) * DH + ((lane >> 4) * 8);
#pragma unroll
      for (int ks = 0; ks < 4; ks++) {
        qf[ks] = *(const f16x8*)(qq + ks * 32);
#pragma unroll
        for (int e = 0; e < 8; e++) qf[ks][e] = (f16)((float)qf[ks][e] * LOG2E);
      }
    }
    float m_[4], l_[4];
    f32x4 o[8] = {};
#pragma unroll
    for (int r = 0; r < 4; r++) { m_[r] = -3e38f; l_[r] = 0.f; }

    {
      int rk0 = ck0 >> 4, rk1 = ck1 >> 4;
      gload16(Kp + (size_t)rk0 * DH + (((ck0 & 15) ^ (rk0 & 7)) * 8), &Ks[0][ck0 * 8]);
      gload16(Kp + (size_t)rk1 * DH + (((ck1 & 15) ^ (rk1 & 7)) * 8), &Ks[0][ck1 * 8]);
      int rv0 = cv0 >> 3, rv1 = cv1 >> 3;
      gload16(Vp + (size_t)rv0 * S_CTX + (((cv0 & 7) ^ (rv0 & 7)) * 8), &Vs[0][cv0 * 8]);
      gload16(Vp + (size_t)rv1 * S_CTX + (((cv1 & 7) ^ (rv1 & 7)) * 8), &Vs[0][cv1 * 8]);
    }
    VMW(0); BAR();

    int cur = 0;
    for (int t = 0; t < NT; t++) {
      if (t + 1 < NT) {
        const f16* Kt = Kp + (size_t)(t + 1) * 64 * DH;
        const f16* Vt = Vp + (size_t)(t + 1) * 64;
        int nb = cur ^ 1;
        int rk0 = ck0 >> 4, rk1 = ck1 >> 4;
        gload16(Kt + (size_t)rk0 * DH + (((ck0 & 15) ^ (rk0 & 7)) * 8), &Ks[nb][ck0 * 8]);
        gload16(Kt + (size_t)rk1 * DH + (((ck1 & 15) ^ (rk1 & 7)) * 8), &Ks[nb][ck1 * 8]);
        int rv0 = cv0 >> 3, rv1 = cv1 >> 3;
        gload16(Vt + (size_t)rv0 * S_CTX + (((cv0 & 7) ^ (rv0 & 7)) * 8), &Vs[nb][cv0 * 8]);
        gload16(Vt + (size_t)rv1 * S_CTX + (((cv1 & 7) ^ (rv1 & 7)) * 8), &Vs[nb][cv1 * 8]);
      }

      const f16* Ksc = Ks[cur];
      const f16* Vsc = Vs[cur];

      f32x4 st[4] = {};
#pragma unroll
      for (int n = 0; n < 4; n++) {
        int rK = n * 16 + (lane & 15);
#pragma unroll
        for (int ks = 0; ks < 4; ks++) {
          int slot = ks * 4 + (lane >> 4);
          f16x8 kf = *(const f16x8*)&Ksc[rK * 128 + ((slot ^ (rK & 7)) << 3)];
          st[n] = MF(qf[ks], kf, st[n]);
        }
      }
      if (t >= 2 * Q) {
#pragma unroll
        for (int n = 0; n < 4; n++)
#pragma unroll
          for (int r = 0; r < 4; r++) {
            int kvc = t * 64 + n * 16 + (lane & 15);
            int qr = q0 + wv * 16 + (lane >> 4) * 4 + r;
            if (kvc > qr) st[n][r] = -3e38f;
          }
      }
      float mx[4];
#pragma unroll
      for (int r = 0; r < 4; r++)
        mx[r] = fmaxf(fmaxf(st[0][r], st[1][r]), fmaxf(st[2][r], st[3][r]));
#pragma unroll
      for (int msk = 1; msk < 16; msk <<= 1)
#pragma unroll
        for (int r = 0; r < 4; r++) mx[r] = fmaxf(mx[r], __shfl_xor(mx[r], msk));
      bool need = false;
#pragma unroll
      for (int r = 0; r < 4; r++) need = need || (mx[r] > m_[r] + 8.0f);
      if (__any(need)) {
#pragma unroll
        for (int r = 0; r < 4; r++) {
          float nm = fmaxf(m_[r], mx[r]);
          float al = __builtin_amdgcn_exp2f(m_[r] - nm);
          m_[r] = nm;
          l_[r] *= al;
#pragma unroll
          for (int j = 0; j < 8; j++) o[j][r] *= al;
        }
      }
      float ps[4] = {0.f, 0.f, 0.f, 0.f};
      float pvv[4][4];
#pragma unroll
      for (int n = 0; n < 4; n++)
#pragma unroll
        for (int r = 0; r < 4; r++) {
          float p = __builtin_amdgcn_exp2f(st[n][r] - m_[r]);
          pvv[n][r] = p; ps[r] += p;
        }
#pragma unroll
      for (int msk = 1; msk < 16; msk <<= 1)
#pragma unroll
        for (int r = 0; r < 4; r++) ps[r] += __shfl_xor(ps[r], msk);
#pragma unroll
      for (int r = 0; r < 4; r++) l_[r] += ps[r];

      f16* Pw = Pl[wv];
#pragma unroll
      for (int n = 0; n < 4; n++)
#pragma unroll
        for (int r = 0; r < 4; r++) {
          int rowp = (lane >> 4) * 4 + r;
          int colp = n * 16 + (lane & 15);
          Pw[rowp * 64 + (((colp >> 3) ^ (rowp & 7)) << 3) + (colp & 7)] = (f16)pvv[n][r];
        }
#pragma unroll
      for (int ks = 0; ks < 2; ks++) {
        int rowp = lane & 15;
        int slotp = ks * 4 + (lane >> 4);
        f16x8 pa = *(const f16x8*)&Pw[rowp * 64 + ((slotp ^ (rowp & 7)) << 3)];
#pragma unroll
        for (int j = 0; j < 8; j++) {
          int rv = j * 16 + (lane & 15);
          int slotv = ks * 4 + (lane >> 4);
          f16x8 vf = *(const f16x8*)&Vsc[rv * 64 + ((slotv ^ (rv & 7)) << 3)];
          o[j] = MF(pa, vf, o[j]);
        }
      }

      VMW(0); BAR();
      cur ^= 1;
    }

#pragma unroll
    for (int j = 0; j < 8; j++)
#pragma unroll
      for (int r = 0; r < 4; r++) {
        int qr = q0 + wv * 16 + (lane >> 4) * 4 + r;
        int dd = h * 128 + j * 16 + (lane & 15);
        ctx[((size_t)(b * S_CTX + qr) * 2048) + dd] = (f16)(o[j][r] / l_[r]);
      }
  }
}

extern "C" void kernel_launch(void* const* d_in, const int* in_sizes, int n_in,
                              void* d_out, int out_size, void* d_ws, size_t ws_size,
                              hipStream_t stream) {
  (void)in_sizes; (void)n_in; (void)out_size; (void)ws_size;
  const float* x  = (const float*)d_in[0];
  const float* Wq = (const float*)d_in[1];
  const float* Wk = (const float*)d_in[2];
  const float* Wv = (const float*)d_in[3];
  const float* Wo = (const float*)d_in[4];
  float* out = (float*)d_out;
  char* ws = (char*)d_ws;

  f16*   xb   = (f16*)(ws);                    // x fp16 [4096][2048]
  f16*   ctxb = (f16*)(ws);                    // reuse (xb dead after QKV)
  f16*   wqT  = (f16*)(ws + 16777216);         // [n][k] fp16, 8 MB each
  f16*   wkT  = (f16*)(ws + 25165824);
  f16*   wvT  = (f16*)(ws + 33554432);
  f16*   woT  = (f16*)(ws + 41943040);
  f16*   qb   = (f16*)(ws + 50331648);         // [b,h,s,d] fp16 (rope applied)
  f16*   kb   = (f16*)(ws + 67108864);
  f16*   vtb  = (f16*)(ws + 83886080);         // [b,h,d,s] fp16
  float* sint = (float*)(ws + 100663296);      // [2048][64]
  float* cost = (float*)(ws + 101187584);

  prep<<<dim3(25088), dim3(256), 0, stream>>>(x, Wq, Wk, Wv, Wo, xb,
                                              wqT, wkT, wvT, woT, sint, cost);
  gemm_qkv<<<dim3(24, 16), dim3(512), 98304, stream>>>(xb, wqT, wkT, wvT,
                                                       qb, kb, vtb, sint, cost);
  attn_k<<<dim3(8, 32), dim3(512), 0, stream>>>(qb, kb, vtb, ctxb);
  gemm8<2><<<dim3(16, 16), dim3(512), 98304, stream>>>(ctxb, woT, nullptr, out);
}